// Round 11
// baseline (217.721 us; speedup 1.0000x reference)
//
#include <hip/hip_runtime.h>
#include <hip/hip_bf16.h>

#define B_   4
#define T_   2048
#define C_   1024
#define H_   16
#define BT_  (B_ * T_)      // 8192
#define NQKV (3 * C_)       // 3072

typedef __attribute__((ext_vector_type(8))) short short8;
typedef __attribute__((ext_vector_type(4))) short short4v;
typedef __attribute__((ext_vector_type(4))) float f32x4;

__device__ inline float b2f(short u) {
    unsigned int x = ((unsigned int)(unsigned short)u) << 16;
    float f;
    __builtin_memcpy(&f, &x, 4);
    return f;
}
__device__ inline short f2b(float f) {
    __hip_bfloat16 h = __float2bfloat16(f);
    unsigned short u;
    __builtin_memcpy(&u, &h, 2);
    return (short)u;
}
__device__ inline f32x4 fz4() { f32x4 z; z[0] = z[1] = z[2] = z[3] = 0.f; return z; }
__device__ inline float exp2_raw(float x) {   // bare v_exp_f32 (=2^x), no libm fixup
    float r;
    asm("v_exp_f32 %0, %1" : "=v"(r) : "v"(x));
    return r;
}

__device__ inline void load_lds16(const void* g, void* l) {
    __builtin_amdgcn_global_load_lds((const __attribute__((address_space(1))) unsigned int*)g,
                                     (__attribute__((address_space(3))) unsigned int*)l,
                                     16, 0, 0);
}
__device__ inline void barrier_nodrain() {
    __builtin_amdgcn_sched_barrier(0);
    __builtin_amdgcn_s_barrier();
    __builtin_amdgcn_sched_barrier(0);
}

// fp32 -> bf16 bulk convert (n multiple of 2048)
__global__ __launch_bounds__(256) void cvt_kernel(const float* __restrict__ in,
                                                  short* __restrict__ out, int n) {
    int i = (blockIdx.x * 256 + threadIdx.x) * 8;
    if (i >= n) return;
    float4 a = *(const float4*)(in + i);
    float4 b = *(const float4*)(in + i + 4);
    short8 s;
    s[0] = f2b(a.x); s[1] = f2b(a.y); s[2] = f2b(a.z); s[3] = f2b(a.w);
    s[4] = f2b(b.x); s[5] = f2b(b.y); s[6] = f2b(b.z); s[7] = f2b(b.w);
    *(short8*)(out + i) = s;
}

// cos/sin table: tab[t*32+i] = (cos, sin) of t * 10000^(-i/32), t<2048, i<32
__global__ __launch_bounds__(256) void rope_table(float2* __restrict__ tab) {
    int idx = blockIdx.x * 256 + threadIdx.x;   // 65536
    int t = idx >> 5, i = idx & 31;
    float inv = exp2f(-(float)i * 0.41524101186092029f);
    float ang = (float)t * inv;
    float s, c;
    sincosf(ang, &s, &c);
    tab[idx] = make_float2(c, s);
}

// C[m][n] = sum_k A[m][k]*Bw[n][k]; A,Bw bf16 [.][K]. 128x256 block, BK=64,
// 4 waves x (128x64) wave-tile (0.375 LDS reads/MFMA). Ring-2 LDS, counted
// vmcnt(12) across raw barriers, chunk-XOR swizzle both sides.
template <int CF32, int ROPE>
__global__ __launch_bounds__(256) void gemm_pipe(const short* __restrict__ Ab,
                                                 const short* __restrict__ Bw,
                                                 void* __restrict__ Cp,
                                                 int M, int N, int K,
                                                 const float2* __restrict__ tab) {
    __shared__ short As[2][128 * 64];
    __shared__ short Bs[2][256 * 64];
    const int tid = threadIdx.x;
    const int l16 = tid & 15, lq = (tid & 63) >> 4;
    const int wid = tid >> 6;          // 0..3 : N-slot of this wave
    const int m0 = blockIdx.x * 128, n0 = blockIdx.y * 256;
    const int NT = K >> 6;

    f32x4 acc[8][4];
#pragma unroll
    for (int i = 0; i < 8; ++i)
#pragma unroll
        for (int j = 0; j < 4; ++j) acc[i][j] = fz4();

    auto stage = [&](int bf, int t) {   // 12 gload_lds per thread
        const int k0 = t * 64;
#pragma unroll
        for (int p = 0; p < 4; ++p) {   // A: 1024 chunks
            int c = p * 256 + tid;
            int r = c >> 3, cs = (c & 7) ^ (r & 7);
            load_lds16(Ab + (size_t)(m0 + r) * K + k0 + cs * 8,
                       &As[bf][(p * 256 + (tid & ~63)) * 8]);
        }
#pragma unroll
        for (int p = 0; p < 8; ++p) {   // B: 2048 chunks
            int c = p * 256 + tid;
            int r = c >> 3, cs = (c & 7) ^ (r & 7);
            load_lds16(Bw + (size_t)(n0 + r) * K + k0 + cs * 8,
                       &Bs[bf][(p * 256 + (tid & ~63)) * 8]);
        }
    };

    stage(0, 0);
    for (int t = 0; t < NT; ++t) {
        if (t + 1 < NT) {
            stage((t + 1) & 1, t + 1);
            asm volatile("s_waitcnt vmcnt(12)" ::: "memory");   // tile t landed; t+1 flying
        } else {
            asm volatile("s_waitcnt vmcnt(0)" ::: "memory");
        }
        barrier_nodrain();
        const short* Ac = As[t & 1];
        const short* Bc = Bs[t & 1];
#pragma unroll
        for (int kk = 0; kk < 2; ++kk) {
            short8 af[8], bfr[4];
#pragma unroll
            for (int mf = 0; mf < 8; ++mf) {
                int row = mf * 16 + l16;
                af[mf] = *(const short8*)&Ac[row * 64 + (((kk * 4 + lq) ^ (row & 7)) * 8)];
            }
#pragma unroll
            for (int nf = 0; nf < 4; ++nf) {
                int row = wid * 64 + nf * 16 + l16;
                bfr[nf] = *(const short8*)&Bc[row * 64 + (((kk * 4 + lq) ^ (row & 7)) * 8)];
            }
            __builtin_amdgcn_s_setprio(1);
#pragma unroll
            for (int mf = 0; mf < 8; ++mf)
#pragma unroll
                for (int nf = 0; nf < 4; ++nf)
                    acc[mf][nf] = __builtin_amdgcn_mfma_f32_16x16x32_bf16(
                        af[mf], bfr[nf], acc[mf][nf], 0, 0, 0);
            __builtin_amdgcn_s_setprio(0);
        }
        barrier_nodrain();   // readers done before next stage overwrites
    }

    if constexpr (ROPE) {
        if (n0 < 2048) {   // block-uniform: Q/K columns only
#pragma unroll
            for (int mf = 0; mf < 8; ++mf)
#pragma unroll
                for (int nf = 0; nf < 4; ++nf) {
                    const int ii = (nf * 16 + l16) >> 1;
                    const float sgn = (l16 & 1) ? 1.0f : -1.0f;
#pragma unroll
                    for (int rr = 0; rr < 4; ++rr) {
                        int row = m0 + mf * 16 + lq * 4 + rr;
                        float v = acc[mf][nf][rr];
                        float p = __shfl_xor(v, 1);
                        float2 cs = tab[(row & (T_ - 1)) * 32 + ii];
                        acc[mf][nf][rr] = v * cs.x + sgn * (p * cs.y);
                    }
                }
        }
    }
#pragma unroll
    for (int mf = 0; mf < 8; ++mf)
#pragma unroll
        for (int nf = 0; nf < 4; ++nf)
#pragma unroll
            for (int rr = 0; rr < 4; ++rr) {
                int row = m0 + mf * 16 + lq * 4 + rr;
                int col = n0 + wid * 64 + nf * 16 + l16;
                if constexpr (CF32)
                    ((float*)Cp)[(size_t)row * N + col] = acc[mf][nf][rr];
                else
                    ((short*)Cp)[(size_t)row * N + col] = f2b(acc[mf][nf][rr]);
            }
}

// V region of qkv -> vT[(b*16+h)*64 + d][t]  (per-(b,h) 64 x 2048, bf16)
__global__ __launch_bounds__(256) void transpose_v(const short* __restrict__ qkv,
                                                   short* __restrict__ vT) {
    const int blk = blockIdx.x;
    const int bh = blk >> 5, tt = blk & 31;
    const int b = bh >> 4, h = bh & 15;
    const int t0 = tt * 64;
    const int tid = threadIdx.x;
    __shared__ int tile[64][65];
#pragma unroll
    for (int p = 0; p < 2; ++p) {
        int c = p * 256 + tid;
        int t = c >> 3, d0 = (c & 7) * 8;
        short8 v = *(const short8*)(qkv + (size_t)(b * T_ + t0 + t) * NQKV + 2 * C_ + h * 64 + d0);
#pragma unroll
        for (int u = 0; u < 8; ++u) tile[t][d0 + u] = v[u];
    }
    __syncthreads();
#pragma unroll
    for (int p = 0; p < 2; ++p) {
        int c = p * 256 + tid;
        int d = c >> 3, tq0 = (c & 7) * 8;
        short8 s;
#pragma unroll
        for (int u = 0; u < 8; ++u) s[u] = (short)tile[tq0 + u][d];
        *(short8*)(vT + (size_t)(bh * 64 + d) * 2048 + t0 + tq0) = s;
    }
}

// MFMA flash attention: block = (b,h,128 q rows), 4 waves x 2 row-groups.
// Base-2 online softmax via raw v_exp_f32, defer-max THR=8, packed b64 P staging.
__global__ __launch_bounds__(256) void attn_mfma(const short* __restrict__ qkv,
                                                 const short* __restrict__ vT,
                                                 short* __restrict__ att) {
    const int blk = blockIdx.x;
    const int bh = blk & 63;               // all heads of a qt dispatch together
    const int qt = 15 - (blk >> 6);        // heavy q-tiles first
    const int b = bh >> 4, h = bh & 15;
    const int q0 = qt * 128;
    const int tid = threadIdx.x;
    const int w = tid >> 6, l = tid & 63;
    const int l16 = l & 15, lq = l >> 4;
    const int e = l16 & 7;                 // row-XOR term for fragment reads

    __shared__ short Ks[2][64 * 64];
    __shared__ short Vs[2][64 * 64];
    __shared__ short Ps[4][16 * 64];

    short8 qf[2][2];
#pragma unroll
    for (int rg = 0; rg < 2; ++rg) {
        const size_t qrow = (size_t)((b * T_) + q0 + rg * 64 + w * 16 + l16) * NQKV + h * 64;
#pragma unroll
        for (int kk = 0; kk < 2; ++kk) {
            short8 raw = *(const short8*)(qkv + qrow + kk * 32 + lq * 8);
            short8 s;
#pragma unroll
            for (int j = 0; j < 8; ++j) s[j] = f2b(0.18033688011112042f * b2f(raw[j])); // 0.125*log2e
            qf[rg][kk] = s;
        }
    }
    f32x4 acc[2][4];
#pragma unroll
    for (int rg = 0; rg < 2; ++rg)
#pragma unroll
        for (int dt = 0; dt < 4; ++dt) acc[rg][dt] = fz4();
    float m_s[2] = {-1e30f, -1e30f}, l_s[2] = {0.f, 0.f};

    const int nt = 2 * qt + 2;
    auto stage = [&](int bf, int t) {   // 4 gload_lds per thread
        const int k0 = t * 64;
        const size_t kbase = (size_t)((b * T_) + k0) * NQKV + C_ + h * 64;
        const size_t vbase = (size_t)(bh * 64) * 2048 + k0;
#pragma unroll
        for (int p = 0; p < 2; ++p) {
            int c = p * 256 + tid;
            int r = c >> 3;
            int cg = (c & 7) ^ (r & 7);
            load_lds16(qkv + kbase + (size_t)r * NQKV + cg * 8,
                       &Ks[bf][(p * 256 + (tid & ~63)) * 8]);
            load_lds16(vT + vbase + (size_t)r * 2048 + cg * 8,
                       &Vs[bf][(p * 256 + (tid & ~63)) * 8]);
        }
    };

    stage(0, 0);
    for (int t = 0; t < nt; ++t) {
        const int k0 = t * 64;
        if (t + 1 < nt) {
            stage((t + 1) & 1, t + 1);
            asm volatile("s_waitcnt vmcnt(4)" ::: "memory");
        } else {
            asm volatile("s_waitcnt vmcnt(0)" ::: "memory");
        }
        barrier_nodrain();
        const short* Kc = Ks[t & 1];
        const short* Vc = Vs[t & 1];
#pragma unroll
        for (int rg = 0; rg < 2; ++rg) {
            if (rg == 0 && t == nt - 1) continue;   // block-uniform skip
            const int qg = q0 + rg * 64 + w * 16 + l16;
            f32x4 sc[4];
#pragma unroll
            for (int ct = 0; ct < 4; ++ct) sc[ct] = fz4();
            __builtin_amdgcn_s_setprio(1);
#pragma unroll
            for (int kk = 0; kk < 2; ++kk)
#pragma unroll
                for (int ct = 0; ct < 4; ++ct) {
                    short8 ak = *(const short8*)&Kc[(ct * 16 + l16) * 64 + (((kk * 4 + lq) ^ e) * 8)];
                    sc[ct] = __builtin_amdgcn_mfma_f32_16x16x32_bf16(ak, qf[rg][kk], sc[ct], 0, 0, 0);
                }
            __builtin_amdgcn_s_setprio(0);
            if (k0 + 63 > q0 + rg * 64 + w * 16) {
#pragma unroll
                for (int ct = 0; ct < 4; ++ct)
#pragma unroll
                    for (int r = 0; r < 4; ++r)
                        if (k0 + ct * 16 + lq * 4 + r > qg) sc[ct][r] = -1e30f;
            }
            // row max (base-2 units); lanes sharing l16 hold one q-row
            float mx = -1e30f;
#pragma unroll
            for (int ct = 0; ct < 4; ++ct)
#pragma unroll
                for (int r = 0; r < 4; ++r) mx = fmaxf(mx, sc[ct][r]);
            mx = fmaxf(mx, __shfl_xor(mx, 16));
            mx = fmaxf(mx, __shfl_xor(mx, 32));
            // defer-max: skip rescale when max growth <= 8 (P bounded by 2^8)
            const bool skip = __all(mx <= m_s[rg] + 8.0f);
            const float mn = skip ? m_s[rg] : fmaxf(m_s[rg], mx);
            float s0 = 0.f;
#pragma unroll
            for (int ct = 0; ct < 4; ++ct) {
                short4v pv;
#pragma unroll
                for (int r = 0; r < 4; ++r) {
                    float p = exp2_raw(sc[ct][r] - mn);
                    pv[r] = f2b(p);
                    s0 += p;
                }
                *(short4v*)&Ps[w][l16 * 64 + (((ct * 2 + (lq >> 1)) ^ e) * 8) + (lq & 1) * 4] = pv;
            }
            s0 += __shfl_xor(s0, 16);
            s0 += __shfl_xor(s0, 32);
            if (skip) {
                l_s[rg] += s0;
            } else {
                float al = exp2_raw(m_s[rg] - mn);
                m_s[rg] = mn;
                l_s[rg] = l_s[rg] * al + s0;
                float albc[4];
#pragma unroll
                for (int r = 0; r < 4; ++r) albc[r] = __shfl(al, lq * 4 + r);
#pragma unroll
                for (int dt = 0; dt < 4; ++dt) {
                    f32x4 a4 = acc[rg][dt];
                    a4[0] *= albc[0]; a4[1] *= albc[1]; a4[2] *= albc[2]; a4[3] *= albc[3];
                    acc[rg][dt] = a4;
                }
            }
            __builtin_amdgcn_s_setprio(1);
#pragma unroll
            for (int kk = 0; kk < 2; ++kk) {
                short8 pa = *(const short8*)&Ps[w][l16 * 64 + (((kk * 4 + lq) ^ e) * 8)];
#pragma unroll
                for (int dt = 0; dt < 4; ++dt) {
                    short8 bv = *(const short8*)&Vc[(dt * 16 + l16) * 64 + (((kk * 4 + lq) ^ e) * 8)];
                    acc[rg][dt] = __builtin_amdgcn_mfma_f32_16x16x32_bf16(pa, bv, acc[rg][dt], 0, 0, 0);
                }
            }
            __builtin_amdgcn_s_setprio(0);
        }
        barrier_nodrain();
    }
#pragma unroll
    for (int rg = 0; rg < 2; ++rg) {
        float lbc[4];
#pragma unroll
        for (int r = 0; r < 4; ++r) lbc[r] = __shfl(l_s[rg], lq * 4 + r);
#pragma unroll
        for (int r = 0; r < 4; ++r) {
            float inv = 1.0f / lbc[r];
            size_t ob = (size_t)((b * T_) + q0 + rg * 64 + w * 16 + lq * 4 + r) * C_ + h * 64 + l16;
#pragma unroll
            for (int dt = 0; dt < 4; ++dt)
                att[ob + dt * 16] = f2b(acc[rg][dt][r] * inv);
        }
    }
}

extern "C" void kernel_launch(void* const* d_in, const int* in_sizes, int n_in,
                              void* d_out, int out_size, void* d_ws, size_t ws_size,
                              hipStream_t stream) {
    const float* x = (const float*)d_in[0];
    const float* Wqkv = (const float*)d_in[1];
    const float* Wproj = (const float*)d_in[2];
    char* ws = (char*)d_ws;

    short* qkv = (short*)ws;                                     // [0, 48MB)
    short* att = (short*)(ws + (size_t)BT_ * NQKV * 2);          // [48MB, 64MB)
    short* wqb = att;                                            // 6MB, dead before att written
    float2* tab = (float2*)(ws + (size_t)BT_ * NQKV * 2 + (size_t)3 * C_ * C_ * 2); // 512KB
    short* wpb = qkv;                                            // 2MB, qkv dead by then
    short* vT  = (short*)d_out;                                  // d_out[0,16MB): V^T scratch
    short* xb  = (short*)((char*)d_out + ((size_t)BT_ * C_ * 2)); // d_out[16,32MB): x bf16

    // 1) rope table + x,Wqkv -> bf16
    rope_table<<<256, 256, 0, stream>>>(tab);
    cvt_kernel<<<(BT_ * C_) / 2048, 256, 0, stream>>>(x, xb, BT_ * C_);
    cvt_kernel<<<(3 * C_ * C_) / 2048, 256, 0, stream>>>(Wqkv, wqb, 3 * C_ * C_);
    // 2) qkv = xb @ Wqkv^T with fused RoPE (bf16 out)
    dim3 g1(BT_ / 128, NQKV / 256);
    gemm_pipe<0, 1><<<g1, 256, 0, stream>>>(xb, wqb, (void*)qkv, BT_, NQKV, C_, tab);
    // 3) V -> vT (per-(b,h) transpose)
    transpose_v<<<64 * 32, 256, 0, stream>>>(qkv, vT);
    // 4) attention
    attn_mfma<<<B_ * H_ * (T_ / 128), 256, 0, stream>>>(qkv, vT, att);
    // 5) Wproj -> bf16
    cvt_kernel<<<(C_ * C_) / 2048, 256, 0, stream>>>(Wproj, wpb, C_ * C_);
    // 6) out = att @ Wproj^T (fp32 out; overwrites vT/xb scratch)
    dim3 g2(BT_ / 128, C_ / 256);
    gemm_pipe<1, 0><<<g2, 256, 0, stream>>>(att, wpb, d_out, BT_, C_, C_, tab);
}

// Round 12
// 206.302 us; speedup vs baseline: 1.0554x; 1.0554x over previous
//
#include <hip/hip_runtime.h>
#include <hip/hip_bf16.h>

#define B_   4
#define T_   2048
#define C_   1024
#define H_   16
#define BT_  (B_ * T_)      // 8192
#define NQKV (3 * C_)       // 3072

typedef __attribute__((ext_vector_type(8))) short short8;
typedef __attribute__((ext_vector_type(4))) short short4v;
typedef __attribute__((ext_vector_type(4))) float f32x4;

__device__ inline float b2f(short u) {
    unsigned int x = ((unsigned int)(unsigned short)u) << 16;
    float f;
    __builtin_memcpy(&f, &x, 4);
    return f;
}
__device__ inline short f2b(float f) {
    __hip_bfloat16 h = __float2bfloat16(f);
    unsigned short u;
    __builtin_memcpy(&u, &h, 2);
    return (short)u;
}
__device__ inline f32x4 fz4() { f32x4 z; z[0] = z[1] = z[2] = z[3] = 0.f; return z; }
__device__ inline float exp2_raw(float x) {   // bare v_exp_f32 (=2^x), no libm fixup
    float r;
    asm("v_exp_f32 %0, %1" : "=v"(r) : "v"(x));
    return r;
}

__device__ inline void load_lds16(const void* g, void* l) {
    __builtin_amdgcn_global_load_lds((const __attribute__((address_space(1))) unsigned int*)g,
                                     (__attribute__((address_space(3))) unsigned int*)l,
                                     16, 0, 0);
}
__device__ inline void barrier_nodrain() {
    __builtin_amdgcn_sched_barrier(0);
    __builtin_amdgcn_s_barrier();
    __builtin_amdgcn_sched_barrier(0);
}

// fp32 -> bf16 bulk convert (n multiple of 2048)
__global__ __launch_bounds__(256) void cvt_kernel(const float* __restrict__ in,
                                                  short* __restrict__ out, int n) {
    int i = (blockIdx.x * 256 + threadIdx.x) * 8;
    if (i >= n) return;
    float4 a = *(const float4*)(in + i);
    float4 b = *(const float4*)(in + i + 4);
    short8 s;
    s[0] = f2b(a.x); s[1] = f2b(a.y); s[2] = f2b(a.z); s[3] = f2b(a.w);
    s[4] = f2b(b.x); s[5] = f2b(b.y); s[6] = f2b(b.z); s[7] = f2b(b.w);
    *(short8*)(out + i) = s;
}

// cos/sin table: tab[t*32+i] = (cos, sin) of t * 10000^(-i/32), t<2048, i<32
__global__ __launch_bounds__(256) void rope_table(float2* __restrict__ tab) {
    int idx = blockIdx.x * 256 + threadIdx.x;   // 65536
    int t = idx >> 5, i = idx & 31;
    float inv = exp2f(-(float)i * 0.41524101186092029f);
    float ang = (float)t * inv;
    float s, c;
    sincosf(ang, &s, &c);
    tab[idx] = make_float2(c, s);
}

// C[m][n] = sum_k A[m][k]*Bw[n][k]; A,Bw bf16 [.][K]. 128x256 block, BK=64,
// 8 waves (2Mx4N, 64x64 wave-tile). RING-3 LDS, prefetch distance 2,
// ONE barrier per K-step, counted vmcnt(6) (never waits in steady state).
template <int CF32, int ROPE>
__global__ __launch_bounds__(512) void gemm_pipe(const short* __restrict__ Ab,
                                                 const short* __restrict__ Bw,
                                                 void* __restrict__ Cp,
                                                 int M, int N, int K,
                                                 const float2* __restrict__ tab) {
    __shared__ short As[3][128 * 64];
    __shared__ short Bs[3][256 * 64];
    const int tid = threadIdx.x;
    const int l16 = tid & 15, lq = (tid & 63) >> 4;
    const int wid = tid >> 6;          // 0..7
    const int wm = wid >> 2, wn = wid & 3;   // 2M x 4N wave grid
    const int m0 = blockIdx.x * 128, n0 = blockIdx.y * 256;
    const int NT = K >> 6;

    f32x4 acc[4][4];
#pragma unroll
    for (int i = 0; i < 4; ++i)
#pragma unroll
        for (int j = 0; j < 4; ++j) acc[i][j] = fz4();

    auto stage = [&](int bf, int t) {   // 6 gload_lds per thread
        const int k0 = t * 64;
#pragma unroll
        for (int p = 0; p < 2; ++p) {
            int c = p * 512 + tid;
            int r = c >> 3, cs = (c & 7) ^ (r & 7);
            load_lds16(Ab + (size_t)(m0 + r) * K + k0 + cs * 8,
                       &As[bf][(p * 512 + (tid & ~63)) * 8]);
        }
#pragma unroll
        for (int p = 0; p < 4; ++p) {
            int c = p * 512 + tid;
            int r = c >> 3, cs = (c & 7) ^ (r & 7);
            load_lds16(Bw + (size_t)(n0 + r) * K + k0 + cs * 8,
                       &Bs[bf][(p * 512 + (tid & ~63)) * 8]);
        }
    };

    stage(0, 0);
    if (NT > 1) stage(1, 1);
    for (int t = 0; t < NT; ++t) {
        // tile t's 6 loads are the oldest outstanding; t+1's (<=6) may still fly
        if (t + 1 < NT) {
            asm volatile("s_waitcnt vmcnt(6)" ::: "memory");
        } else {
            asm volatile("s_waitcnt vmcnt(0)" ::: "memory");
        }
        barrier_nodrain();               // all waves: tile t resident; iter t-1 reads done
        if (t + 2 < NT) stage((t + 2) % 3, t + 2);
        const short* Ac = As[t % 3];
        const short* Bc = Bs[t % 3];
#pragma unroll
        for (int kk = 0; kk < 2; ++kk) {
            short8 af[4], bfr[4];
#pragma unroll
            for (int mf = 0; mf < 4; ++mf) {
                int row = wm * 64 + mf * 16 + l16;
                af[mf] = *(const short8*)&Ac[row * 64 + (((kk * 4 + lq) ^ (row & 7)) * 8)];
            }
#pragma unroll
            for (int nf = 0; nf < 4; ++nf) {
                int row = wn * 64 + nf * 16 + l16;
                bfr[nf] = *(const short8*)&Bc[row * 64 + (((kk * 4 + lq) ^ (row & 7)) * 8)];
            }
            __builtin_amdgcn_s_setprio(1);
#pragma unroll
            for (int mf = 0; mf < 4; ++mf)
#pragma unroll
                for (int nf = 0; nf < 4; ++nf)
                    acc[mf][nf] = __builtin_amdgcn_mfma_f32_16x16x32_bf16(
                        af[mf], bfr[nf], acc[mf][nf], 0, 0, 0);
            __builtin_amdgcn_s_setprio(0);
        }
        // no bottom barrier: next iteration's top barrier provides the ordering
    }

    if constexpr (ROPE) {
        if (n0 < 2048) {   // block-uniform: Q/K columns only
#pragma unroll
            for (int mf = 0; mf < 4; ++mf)
#pragma unroll
                for (int nf = 0; nf < 4; ++nf) {
                    const int ii = (nf * 16 + l16) >> 1;
                    const float sgn = (l16 & 1) ? 1.0f : -1.0f;
#pragma unroll
                    for (int rr = 0; rr < 4; ++rr) {
                        int row = m0 + wm * 64 + mf * 16 + lq * 4 + rr;
                        float v = acc[mf][nf][rr];
                        float p = __shfl_xor(v, 1);
                        float2 cs = tab[(row & (T_ - 1)) * 32 + ii];
                        acc[mf][nf][rr] = v * cs.x + sgn * (p * cs.y);
                    }
                }
        }
    }
#pragma unroll
    for (int mf = 0; mf < 4; ++mf)
#pragma unroll
        for (int nf = 0; nf < 4; ++nf)
#pragma unroll
            for (int rr = 0; rr < 4; ++rr) {
                int row = m0 + wm * 64 + mf * 16 + lq * 4 + rr;
                int col = n0 + wn * 64 + nf * 16 + l16;
                if constexpr (CF32)
                    ((float*)Cp)[(size_t)row * N + col] = acc[mf][nf][rr];
                else
                    ((short*)Cp)[(size_t)row * N + col] = f2b(acc[mf][nf][rr]);
            }
}

// V region of qkv -> vT[(b*16+h)*64 + d][t]  (per-(b,h) 64 x 2048, bf16)
__global__ __launch_bounds__(256) void transpose_v(const short* __restrict__ qkv,
                                                   short* __restrict__ vT) {
    const int blk = blockIdx.x;
    const int bh = blk >> 5, tt = blk & 31;
    const int b = bh >> 4, h = bh & 15;
    const int t0 = tt * 64;
    const int tid = threadIdx.x;
    __shared__ int tile[64][65];
#pragma unroll
    for (int p = 0; p < 2; ++p) {
        int c = p * 256 + tid;
        int t = c >> 3, d0 = (c & 7) * 8;
        short8 v = *(const short8*)(qkv + (size_t)(b * T_ + t0 + t) * NQKV + 2 * C_ + h * 64 + d0);
#pragma unroll
        for (int u = 0; u < 8; ++u) tile[t][d0 + u] = v[u];
    }
    __syncthreads();
#pragma unroll
    for (int p = 0; p < 2; ++p) {
        int c = p * 256 + tid;
        int d = c >> 3, tq0 = (c & 7) * 8;
        short8 s;
#pragma unroll
        for (int u = 0; u < 8; ++u) s[u] = (short)tile[tq0 + u][d];
        *(short8*)(vT + (size_t)(bh * 64 + d) * 2048 + t0 + tq0) = s;
    }
}

// MFMA flash attention: block = (b,h,128 q rows), 4 waves x 2 row-groups.
// Base-2 online softmax via raw v_exp_f32, defer-max THR=8, packed b64 P staging.
__global__ __launch_bounds__(256) void attn_mfma(const short* __restrict__ qkv,
                                                 const short* __restrict__ vT,
                                                 short* __restrict__ att) {
    const int blk = blockIdx.x;
    const int bh = blk & 63;               // all heads of a qt dispatch together
    const int qt = 15 - (blk >> 6);        // heavy q-tiles first
    const int b = bh >> 4, h = bh & 15;
    const int q0 = qt * 128;
    const int tid = threadIdx.x;
    const int w = tid >> 6, l = tid & 63;
    const int l16 = l & 15, lq = l >> 4;
    const int e = l16 & 7;                 // row-XOR term for fragment reads

    __shared__ short Ks[2][64 * 64];
    __shared__ short Vs[2][64 * 64];
    __shared__ short Ps[4][16 * 64];

    short8 qf[2][2];
#pragma unroll
    for (int rg = 0; rg < 2; ++rg) {
        const size_t qrow = (size_t)((b * T_) + q0 + rg * 64 + w * 16 + l16) * NQKV + h * 64;
#pragma unroll
        for (int kk = 0; kk < 2; ++kk) {
            short8 raw = *(const short8*)(qkv + qrow + kk * 32 + lq * 8);
            short8 s;
#pragma unroll
            for (int j = 0; j < 8; ++j) s[j] = f2b(0.18033688011112042f * b2f(raw[j])); // 0.125*log2e
            qf[rg][kk] = s;
        }
    }
    f32x4 acc[2][4];
#pragma unroll
    for (int rg = 0; rg < 2; ++rg)
#pragma unroll
        for (int dt = 0; dt < 4; ++dt) acc[rg][dt] = fz4();
    float m_s[2] = {-1e30f, -1e30f}, l_s[2] = {0.f, 0.f};

    const int nt = 2 * qt + 2;
    auto stage = [&](int bf, int t) {   // 4 gload_lds per thread
        const int k0 = t * 64;
        const size_t kbase = (size_t)((b * T_) + k0) * NQKV + C_ + h * 64;
        const size_t vbase = (size_t)(bh * 64) * 2048 + k0;
#pragma unroll
        for (int p = 0; p < 2; ++p) {
            int c = p * 256 + tid;
            int r = c >> 3;
            int cg = (c & 7) ^ (r & 7);
            load_lds16(qkv + kbase + (size_t)r * NQKV + cg * 8,
                       &Ks[bf][(p * 256 + (tid & ~63)) * 8]);
            load_lds16(vT + vbase + (size_t)r * 2048 + cg * 8,
                       &Vs[bf][(p * 256 + (tid & ~63)) * 8]);
        }
    };

    stage(0, 0);
    for (int t = 0; t < nt; ++t) {
        const int k0 = t * 64;
        if (t + 1 < nt) {
            stage((t + 1) & 1, t + 1);
            asm volatile("s_waitcnt vmcnt(4)" ::: "memory");
        } else {
            asm volatile("s_waitcnt vmcnt(0)" ::: "memory");
        }
        barrier_nodrain();
        const short* Kc = Ks[t & 1];
        const short* Vc = Vs[t & 1];
#pragma unroll
        for (int rg = 0; rg < 2; ++rg) {
            if (rg == 0 && t == nt - 1) continue;   // block-uniform skip
            const int qg = q0 + rg * 64 + w * 16 + l16;
            f32x4 sc[4];
#pragma unroll
            for (int ct = 0; ct < 4; ++ct) sc[ct] = fz4();
            __builtin_amdgcn_s_setprio(1);
#pragma unroll
            for (int kk = 0; kk < 2; ++kk)
#pragma unroll
                for (int ct = 0; ct < 4; ++ct) {
                    short8 ak = *(const short8*)&Kc[(ct * 16 + l16) * 64 + (((kk * 4 + lq) ^ e) * 8)];
                    sc[ct] = __builtin_amdgcn_mfma_f32_16x16x32_bf16(ak, qf[rg][kk], sc[ct], 0, 0, 0);
                }
            __builtin_amdgcn_s_setprio(0);
            if (k0 + 63 > q0 + rg * 64 + w * 16) {
#pragma unroll
                for (int ct = 0; ct < 4; ++ct)
#pragma unroll
                    for (int r = 0; r < 4; ++r)
                        if (k0 + ct * 16 + lq * 4 + r > qg) sc[ct][r] = -1e30f;
            }
            // row max (base-2 units); lanes sharing l16 hold one q-row
            float mx = -1e30f;
#pragma unroll
            for (int ct = 0; ct < 4; ++ct)
#pragma unroll
                for (int r = 0; r < 4; ++r) mx = fmaxf(mx, sc[ct][r]);
            mx = fmaxf(mx, __shfl_xor(mx, 16));
            mx = fmaxf(mx, __shfl_xor(mx, 32));
            // defer-max: skip rescale when max growth <= 8 (P bounded by 2^8)
            const bool skip = __all(mx <= m_s[rg] + 8.0f);
            const float mn = skip ? m_s[rg] : fmaxf(m_s[rg], mx);
            float s0 = 0.f;
#pragma unroll
            for (int ct = 0; ct < 4; ++ct) {
                short4v pv;
#pragma unroll
                for (int r = 0; r < 4; ++r) {
                    float p = exp2_raw(sc[ct][r] - mn);
                    pv[r] = f2b(p);
                    s0 += p;
                }
                *(short4v*)&Ps[w][l16 * 64 + (((ct * 2 + (lq >> 1)) ^ e) * 8) + (lq & 1) * 4] = pv;
            }
            s0 += __shfl_xor(s0, 16);
            s0 += __shfl_xor(s0, 32);
            if (skip) {
                l_s[rg] += s0;
            } else {
                float al = exp2_raw(m_s[rg] - mn);
                m_s[rg] = mn;
                l_s[rg] = l_s[rg] * al + s0;
                float albc[4];
#pragma unroll
                for (int r = 0; r < 4; ++r) albc[r] = __shfl(al, lq * 4 + r);
#pragma unroll
                for (int dt = 0; dt < 4; ++dt) {
                    f32x4 a4 = acc[rg][dt];
                    a4[0] *= albc[0]; a4[1] *= albc[1]; a4[2] *= albc[2]; a4[3] *= albc[3];
                    acc[rg][dt] = a4;
                }
            }
            __builtin_amdgcn_s_setprio(1);
#pragma unroll
            for (int kk = 0; kk < 2; ++kk) {
                short8 pa = *(const short8*)&Ps[w][l16 * 64 + (((kk * 4 + lq) ^ e) * 8)];
#pragma unroll
                for (int dt = 0; dt < 4; ++dt) {
                    short8 bv = *(const short8*)&Vc[(dt * 16 + l16) * 64 + (((kk * 4 + lq) ^ e) * 8)];
                    acc[rg][dt] = __builtin_amdgcn_mfma_f32_16x16x32_bf16(pa, bv, acc[rg][dt], 0, 0, 0);
                }
            }
            __builtin_amdgcn_s_setprio(0);
        }
        barrier_nodrain();
    }
#pragma unroll
    for (int rg = 0; rg < 2; ++rg) {
        float lbc[4];
#pragma unroll
        for (int r = 0; r < 4; ++r) lbc[r] = __shfl(l_s[rg], lq * 4 + r);
#pragma unroll
        for (int r = 0; r < 4; ++r) {
            float inv = 1.0f / lbc[r];
            size_t ob = (size_t)((b * T_) + q0 + rg * 64 + w * 16 + lq * 4 + r) * C_ + h * 64 + l16;
#pragma unroll
            for (int dt = 0; dt < 4; ++dt)
                att[ob + dt * 16] = f2b(acc[rg][dt][r] * inv);
        }
    }
}

extern "C" void kernel_launch(void* const* d_in, const int* in_sizes, int n_in,
                              void* d_out, int out_size, void* d_ws, size_t ws_size,
                              hipStream_t stream) {
    const float* x = (const float*)d_in[0];
    const float* Wqkv = (const float*)d_in[1];
    const float* Wproj = (const float*)d_in[2];
    char* ws = (char*)d_ws;

    short* qkv = (short*)ws;                                     // [0, 48MB)
    short* att = (short*)(ws + (size_t)BT_ * NQKV * 2);          // [48MB, 64MB)
    short* wqb = att;                                            // 6MB, dead before att written
    float2* tab = (float2*)(ws + (size_t)BT_ * NQKV * 2 + (size_t)3 * C_ * C_ * 2); // 512KB
    short* wpb = qkv;                                            // 2MB, qkv dead by then
    short* vT  = (short*)d_out;                                  // d_out[0,16MB): V^T scratch
    short* xb  = (short*)((char*)d_out + ((size_t)BT_ * C_ * 2)); // d_out[16,32MB): x bf16

    // 1) rope table + x,Wqkv -> bf16
    rope_table<<<256, 256, 0, stream>>>(tab);
    cvt_kernel<<<(BT_ * C_) / 2048, 256, 0, stream>>>(x, xb, BT_ * C_);
    cvt_kernel<<<(3 * C_ * C_) / 2048, 256, 0, stream>>>(Wqkv, wqb, 3 * C_ * C_);
    // 2) qkv = xb @ Wqkv^T with fused RoPE (bf16 out)
    dim3 g1(BT_ / 128, NQKV / 256);
    gemm_pipe<0, 1><<<g1, 512, 0, stream>>>(xb, wqb, (void*)qkv, BT_, NQKV, C_, tab);
    // 3) V -> vT (per-(b,h) transpose)
    transpose_v<<<64 * 32, 256, 0, stream>>>(qkv, vT);
    // 4) attention
    attn_mfma<<<B_ * H_ * (T_ / 128), 256, 0, stream>>>(qkv, vT, att);
    // 5) Wproj -> bf16
    cvt_kernel<<<(C_ * C_) / 2048, 256, 0, stream>>>(Wproj, wpb, C_ * C_);
    // 6) out = att @ Wproj^T (fp32 out; overwrites vT/xb scratch)
    dim3 g2(BT_ / 128, C_ / 256);
    gemm_pipe<1, 0><<<g2, 512, 0, stream>>>(att, wpb, d_out, BT_, C_, C_, tab);
}